// Round 1
// 839.816 us; speedup vs baseline: 1.6926x; 1.6926x over previous
//
#include <hip/hip_runtime.h>

// GridSampler bilinear, align_corners=True, border padding.
// z: [N=8, C=64, IH=256, IW=256] fp32, grid: [N, H=512, W=512, 2] fp32
// out: [N, C, H, W] fp32
//
// V2 strategy: the baseline was bound by divergent-gather address throughput
// (~1 cache-line lookup/CU/cycle; 536M scalar gather dwords). Since the 4
// bilinear corner indices are identical for all 64 channels, we pre-transpose
// z to NHWC in the workspace (channels innermost, 256 B per spatial point).
// The sampler then gathers each corner as a coalesced 16-lane x dwordx4
// (256 B) read: 4x fewer gather instructions, ~4x fewer lines per wave.
// Each thread owns 4 channels x 4 consecutive w; a 4x4 register transpose
// gives coalesced NCHW stores (4 lanes per 64B line), nontemporal to keep
// L2 for gathers.

constexpr int N  = 8;
constexpr int C  = 64;
constexpr int IH = 256;
constexpr int IW = 256;
constexpr int H  = 512;
constexpr int W  = 512;

typedef float floatx4 __attribute__((ext_vector_type(4)));

// ---------------- z[N][C][IH*IW] -> zt[N][IH*IW][C] ----------------------
__global__ __launch_bounds__(256) void transpose_kernel(
    const float* __restrict__ z, float* __restrict__ zt) {
  __shared__ float lds[64][65];  // [c][s], padded
  int b  = blockIdx.x;
  int s0 = (b & 1023) << 6;  // 64 spatial positions per block
  int n  = b >> 10;
  int t  = threadIdx.x;

  const float* zp = z + (size_t)n * (C * IH * IW) + s0;
  // phase A: coalesced read along spatial, 4 channels per thread
  {
    int sv = (t & 15) << 2;
    int c0 = t >> 4;  // 0..15
#pragma unroll
    for (int r = 0; r < 4; ++r) {
      int c = c0 + (r << 4);
      floatx4 v = *(const floatx4*)(zp + (size_t)c * (IH * IW) + sv);
      lds[c][sv + 0] = v[0];
      lds[c][sv + 1] = v[1];
      lds[c][sv + 2] = v[2];
      lds[c][sv + 3] = v[3];
    }
  }
  __syncthreads();
  // phase B: coalesced write along channel
  {
    int c4 = (t & 15) << 2;
    int s_ = t >> 4;  // 0..15
    float* op = zt + ((size_t)n * (IH * IW) + s0) * C;
#pragma unroll
    for (int r = 0; r < 4; ++r) {
      int s = s_ + (r << 4);
      floatx4 v = {lds[c4 + 0][s], lds[c4 + 1][s], lds[c4 + 2][s],
                   lds[c4 + 3][s]};
      *(floatx4*)(op + (size_t)s * C + c4) = v;
    }
  }
}

// ---------------- sampler on NHWC zt -------------------------------------
__global__ __launch_bounds__(256) void sample_nhwc_kernel(
    const float* __restrict__ zt, const float* __restrict__ grid,
    float* __restrict__ out) {
  int t  = threadIdx.x;
  int c4 = (t & 15) << 2;  // channel group: c4..c4+3
  int wq = t >> 4;         // 0..15 -> 4 consecutive w positions
  int b  = blockIdx.x;
  int wt = b & (W / 64 - 1);  // 8 w-tiles of 64
  int nh = b >> 3;
  int h  = nh & (H - 1);
  int n  = nh >> 9;
  int w0 = (wt << 6) + (wq << 2);

  const float2* gp = (const float2*)grid + ((size_t)(n * H + h) * W + w0);
  const float* ztn = zt + (size_t)n * (IH * IW * C);

  floatx4 acc[4];
#pragma unroll
  for (int j = 0; j < 4; ++j) {
    float2 g  = gp[j];
    float  ix = (g.x + 1.0f) * 0.5f * (IW - 1);
    float  iy = (g.y + 1.0f) * 0.5f * (IH - 1);
    float  fx = floorf(ix);
    float  fy = floorf(iy);
    float  tx = ix - fx;
    float  ty = iy - fy;
    int x0 = min(max((int)fx, 0), IW - 1);
    int x1 = min(max((int)fx + 1, 0), IW - 1);
    int y0 = min(max((int)fy, 0), IH - 1);
    int y1 = min(max((int)fy + 1, 0), IH - 1);
    const float* r0 = ztn + (((y0 << 8) + x0) << 6) + c4;
    const float* r1 = ztn + (((y0 << 8) + x1) << 6) + c4;
    const float* r2 = ztn + (((y1 << 8) + x0) << 6) + c4;
    const float* r3 = ztn + (((y1 << 8) + x1) << 6) + c4;
    floatx4 v00 = *(const floatx4*)r0;
    floatx4 v01 = *(const floatx4*)r1;
    floatx4 v10 = *(const floatx4*)r2;
    floatx4 v11 = *(const floatx4*)r3;
    float w00 = (1.0f - tx) * (1.0f - ty);
    float w01 = tx * (1.0f - ty);
    float w10 = (1.0f - tx) * ty;
    float w11 = tx * ty;
    acc[j] = w00 * v00 + w01 * v01 + w10 * v10 + w11 * v11;
  }

  // 4x4 register transpose; store NCHW rows (16B per lane, 64B lines
  // completed by the 4 wq-groups sharing each channel row).
  float* on = out + (((size_t)(n * C) * H + h) * W) + w0;
#pragma unroll
  for (int i = 0; i < 4; ++i) {
    floatx4 s = {acc[0][i], acc[1][i], acc[2][i], acc[3][i]};
    __builtin_nontemporal_store(s, (floatx4*)(on + (size_t)(c4 + i) * (H * W)));
  }
}

// ---------------- fallback (baseline) if workspace too small -------------
__global__ __launch_bounds__(256) void grid_sample_kernel(
    const float* __restrict__ z, const float* __restrict__ grid,
    float* __restrict__ out) {
  int t  = blockIdx.x * blockDim.x + threadIdx.x;
  int wq = t & (W / 4 - 1);
  int nh = t >> 7;
  int h  = nh & (H - 1);
  int n  = nh >> 9;
  int w0 = wq << 2;

  const float2* gptr = (const float2*)grid + ((size_t)(n * H + h) * W + w0);

  int   i00[4], i01[4], i10[4], i11[4];
  float w00[4], w01[4], w10[4], w11[4];

#pragma unroll
  for (int j = 0; j < 4; ++j) {
    float2 g  = gptr[j];
    float  ix = (g.x + 1.0f) * 0.5f * (IW - 1);
    float  iy = (g.y + 1.0f) * 0.5f * (IH - 1);
    float  fx = floorf(ix);
    float  fy = floorf(iy);
    float  tx = ix - fx;
    float  ty = iy - fy;
    w00[j] = (1.0f - tx) * (1.0f - ty);
    w01[j] = tx * (1.0f - ty);
    w10[j] = (1.0f - tx) * ty;
    w11[j] = tx * ty;
    int x0 = min(max((int)fx, 0), IW - 1);
    int x1 = min(max((int)fx + 1, 0), IW - 1);
    int y0 = min(max((int)fy, 0), IH - 1);
    int y1 = min(max((int)fy + 1, 0), IH - 1);
    i00[j] = y0 * IW + x0;
    i01[j] = y0 * IW + x1;
    i10[j] = y1 * IW + x0;
    i11[j] = y1 * IW + x1;
  }

  const float* zn = z + (size_t)n * C * IH * IW;
  float* on = out + (size_t)n * C * H * W + (size_t)h * W + w0;

  for (int c = 0; c < C; ++c) {
    const float* __restrict__ zp = zn + (size_t)c * (IH * IW);
    floatx4 r;
#pragma unroll
    for (int j = 0; j < 4; ++j) {
      r[j] = w00[j] * zp[i00[j]] + w01[j] * zp[i01[j]] +
             w10[j] * zp[i10[j]] + w11[j] * zp[i11[j]];
    }
    __builtin_nontemporal_store(r, (floatx4*)(on + (size_t)c * (H * W)));
  }
}

extern "C" void kernel_launch(void* const* d_in, const int* in_sizes, int n_in,
                              void* d_out, int out_size, void* d_ws,
                              size_t ws_size, hipStream_t stream) {
  const float* z    = (const float*)d_in[0];
  const float* grid = (const float*)d_in[1];
  float*       out  = (float*)d_out;

  size_t need = (size_t)N * C * IH * IW * sizeof(float);  // 128 MiB
  if (d_ws != nullptr && ws_size >= need) {
    float* zt = (float*)d_ws;
    transpose_kernel<<<dim3(N * (IH * IW / 64)), dim3(256), 0, stream>>>(z, zt);
    sample_nhwc_kernel<<<dim3(N * H * (W / 64)), dim3(256), 0, stream>>>(
        zt, grid, out);
  } else {
    int threads = N * H * W / 4;  // 524288
    grid_sample_kernel<<<dim3(threads / 256), dim3(256), 0, stream>>>(z, grid,
                                                                      out);
  }
}